// Round 1
// baseline (1351.338 us; speedup 1.0000x reference)
//
#include <hip/hip_runtime.h>
#include <math.h>

// Problem constants (B, L, H, DH, DV) = (4, 4096, 16, 128, 128), CHUNK=1024
#define Bb   4
#define Ll   4096
#define Hh   16
#define DHd  128
#define DVd  128
#define CHk  1024
#define NCc  4

typedef __bf16 bf16x8 __attribute__((ext_vector_type(8)));
typedef float  f32x4  __attribute__((ext_vector_type(4)));

static __device__ __forceinline__ unsigned short f32_to_bf16(float f) {
  unsigned int u = __float_as_uint(f);
  u += 0x7FFFu + ((u >> 16) & 1u);   // round-to-nearest-even
  return (unsigned short)(u >> 16);
}

// ---------------- kernel 1: RoPE cos/sin table [L][64] ----------------
__global__ void rope_table_k(float2* __restrict__ table) {
  int idx = blockIdx.x * 256 + threadIdx.x;
  if (idx >= Ll * 64) return;
  int l = idx >> 6, j = idx & 63;
  float inv_freq = expf((float)j * (-logf(10000.0f) / 64.0f));
  float ang = (float)l * inv_freq;
  float s, c;
  sincosf(ang, &s, &c);
  table[idx] = make_float2(c, s);
}

// ---------- kernel 2: RoPE + scale + bf16 cast for q and k ----------
__global__ void rope_apply_k(const float* __restrict__ q, const float* __restrict__ k,
                             const float2* __restrict__ table,
                             unsigned short* __restrict__ qr,
                             unsigned short* __restrict__ kr) {
  int idx = blockIdx.x * 256 + threadIdx.x;     // B*L*H*64 = 2^24 threads
  int j = idx & 63;
  int h = (idx >> 6) & (Hh - 1);
  int l = (idx >> 10) & (Ll - 1);
  int b = idx >> 22;
  long base = ((long)((b * Ll + l) * Hh + h)) * DHd;
  float2 cs = table[l * 64 + j];
  float q1 = q[base + j], q2 = q[base + 64 + j];
  float k1 = k[base + j], k2 = k[base + 64 + j];
  const float sc = 0.08838834764831845f;        // 1/sqrt(128), folded into q
  qr[base + j]      = f32_to_bf16((q1 * cs.x - q2 * cs.y) * sc);
  qr[base + 64 + j] = f32_to_bf16((q1 * cs.y + q2 * cs.x) * sc);
  kr[base + j]      = f32_to_bf16(k1 * cs.x - k2 * cs.y);
  kr[base + 64 + j] = f32_to_bf16(k1 * cs.y + k2 * cs.x);
}

// ------- kernel 3: V -> bf16, transposed per (b,n,h): vt[dv][kv] -------
__global__ void vtrans_k(const float* __restrict__ v, unsigned short* __restrict__ vt) {
  int bid = blockIdx.x;            // (b,n,h,kb): 4*4*16*16 = 4096 blocks
  int kb = bid & 15;               // 64-row kv block
  int h  = (bid >> 4) & 15;
  int n  = (bid >> 8) & 3;
  int b  = bid >> 10;
  __shared__ __align__(16) unsigned short tile[DVd][65];   // +1 pad
  int tid = threadIdx.x;
#pragma unroll
  for (int it = 0; it < 32; ++it) {
    int idx = it * 256 + tid;      // 64*128 elements
    int r = idx >> 7;              // kv row in block
    int c = idx & 127;             // dv
    float val = v[((long)((b * Ll + n * CHk + kb * 64 + r) * Hh + h)) * DVd + c];
    tile[c][r] = f32_to_bf16(val);
  }
  __syncthreads();
  long obase = ((long)(((b * NCc + n) * Hh + h))) * DVd * CHk + kb * 64;
#pragma unroll
  for (int it = 0; it < 32; ++it) {
    int idx = it * 256 + tid;
    int dv = idx >> 6;
    int kc = idx & 63;
    vt[obase + (long)dv * CHk + kc] = tile[dv][kc];
  }
}

// ---------------- kernel 4: chunk-causal flash attention ----------------
// block = 256 thr (4 waves), 64 q-rows per block (16 per wave), KV tiles of 32.
__global__ void attn_k(const unsigned short* __restrict__ qr,
                       const unsigned short* __restrict__ kr,
                       const unsigned short* __restrict__ vt,
                       float* __restrict__ out) {
  int bid = blockIdx.x;
  int qt = 15 - (bid & 15);        // reversed: heavy (large-qt) blocks first
  int h  = (bid >> 4) & 15;
  int n  = (bid >> 8) & 3;
  int b  = bid >> 10;
  int tid  = threadIdx.x;
  int wid  = tid >> 6;
  int lane = tid & 63;
  int lg = lane >> 4;              // lane group 0..3
  int lc = lane & 15;              // lane in group

  __shared__ __align__(16) unsigned short plds[4][16][32];  // per-wave P tile

  int qrow0 = qt * 64 + wid * 16;  // wave's first q row within chunk

  // Q fragments, hoisted: A[m=lc][k = lg*8+e + 32*ks]
  const unsigned short* qrow =
      qr + ((long)((b * Ll + n * CHk + qrow0 + lc) * Hh + h)) * DHd;
  bf16x8 qf[4];
#pragma unroll
  for (int ks = 0; ks < 4; ++ks)
    qf[ks] = *reinterpret_cast<const bf16x8*>(qrow + ks * 32 + lg * 8);

  f32x4 oacc[8];
#pragma unroll
  for (int i = 0; i < 8; ++i) oacc[i] = (f32x4){0.f, 0.f, 0.f, 0.f};
  float mrow[4], lrow[4];
#pragma unroll
  for (int r = 0; r < 4; ++r) { mrow[r] = -1e30f; lrow[r] = 0.f; }

  const unsigned short* krb = kr + ((long)((b * Ll + n * CHk) * Hh + h)) * DHd;
  const unsigned short* vtb = vt + ((long)(((b * NCc + n) * Hh + h))) * DVd * CHk;

  int nkv = 2 * qt + 2;            // causal: only tiles with col <= qrow0+63
  for (int kvt = 0; kvt < nkv; ++kvt) {
    int kvb = kvt * 32;

    // ---- S = Q K^T  (two 16x16 D-tiles over 32 kv cols) ----
    f32x4 sacc[2];
    sacc[0] = (f32x4){0.f, 0.f, 0.f, 0.f};
    sacc[1] = (f32x4){0.f, 0.f, 0.f, 0.f};
#pragma unroll
    for (int ct = 0; ct < 2; ++ct) {
      const unsigned short* kp = krb + (long)(kvb + ct * 16 + lc) * (Hh * DHd) + lg * 8;
#pragma unroll
      for (int ks = 0; ks < 4; ++ks) {
        bf16x8 kf = *reinterpret_cast<const bf16x8*>(kp + ks * 32);
        sacc[ct] = __builtin_amdgcn_mfma_f32_16x16x32_bf16(qf[ks], kf, sacc[ct], 0, 0, 0);
      }
    }

    // ---- causal mask + online softmax (rows live in 16-lane groups) ----
    float p[2][4];
#pragma unroll
    for (int ct = 0; ct < 2; ++ct) {
      int col = kvb + ct * 16 + lc;
#pragma unroll
      for (int r = 0; r < 4; ++r) {
        float s = sacc[ct][r];
        p[ct][r] = (col <= qrow0 + lg * 4 + r) ? s : -1e30f;
      }
    }
#pragma unroll
    for (int r = 0; r < 4; ++r) {
      float tmax = fmaxf(p[0][r], p[1][r]);
      tmax = fmaxf(tmax, __shfl_xor(tmax, 1));
      tmax = fmaxf(tmax, __shfl_xor(tmax, 2));
      tmax = fmaxf(tmax, __shfl_xor(tmax, 4));
      tmax = fmaxf(tmax, __shfl_xor(tmax, 8));
      float mnew = fmaxf(mrow[r], tmax);
      float corr = __expf(mrow[r] - mnew);
      mrow[r] = mnew;
      float p0 = __expf(p[0][r] - mnew);
      float p1 = __expf(p[1][r] - mnew);
      p[0][r] = p0; p[1][r] = p1;
      float ps = p0 + p1;
      ps += __shfl_xor(ps, 1);
      ps += __shfl_xor(ps, 2);
      ps += __shfl_xor(ps, 4);
      ps += __shfl_xor(ps, 8);
      lrow[r] = lrow[r] * corr + ps;
#pragma unroll
      for (int dt = 0; dt < 8; ++dt) oacc[dt][r] *= corr;
    }

    // ---- P (D-layout) -> LDS -> A-fragment layout ----
#pragma unroll
    for (int ct = 0; ct < 2; ++ct)
#pragma unroll
      for (int r = 0; r < 4; ++r)
        plds[wid][lg * 4 + r][ct * 16 + lc] = f32_to_bf16(p[ct][r]);
    // same-wave DS ops execute in order; aliasing orders write->read
    bf16x8 pf = *reinterpret_cast<const bf16x8*>(&plds[wid][lc][lg * 8]);

    // ---- O += P V  (8 dv-chunks of 16) ----
#pragma unroll
    for (int dt = 0; dt < 8; ++dt) {
      const unsigned short* vp = vtb + (long)(dt * 16 + lc) * CHk + kvb + lg * 8;
      bf16x8 vf = *reinterpret_cast<const bf16x8*>(vp);
      oacc[dt] = __builtin_amdgcn_mfma_f32_16x16x32_bf16(pf, vf, oacc[dt], 0, 0, 0);
    }
  }

  // ---- epilogue: normalize and store f32 ----
  long ob = (long)(b * Ll + n * CHk + qrow0 + lg * 4) * (Hh * DVd) + h * DVd + lc;
#pragma unroll
  for (int r = 0; r < 4; ++r) {
    float invl = 1.0f / lrow[r];
#pragma unroll
    for (int dt = 0; dt < 8; ++dt)
      out[ob + (long)r * (Hh * DVd) + dt * 16] = oacc[dt][r] * invl;
  }
}

extern "C" void kernel_launch(void* const* d_in, const int* in_sizes, int n_in,
                              void* d_out, int out_size, void* d_ws, size_t ws_size,
                              hipStream_t stream) {
  const float* q = (const float*)d_in[0];
  const float* k = (const float*)d_in[1];
  const float* v = (const float*)d_in[2];
  float* out = (float*)d_out;

  // workspace layout: table(2MB) | qr(64MB) | kr(64MB) | vt(64MB)  => ~194MB
  char* ws = (char*)d_ws;
  float2* table = (float2*)ws;
  unsigned short* qrw = (unsigned short*)(ws + (2l << 20));
  unsigned short* krw = qrw + (long)Bb * Ll * Hh * DHd;
  unsigned short* vtw = krw + (long)Bb * Ll * Hh * DHd;

  hipLaunchKernelGGL(rope_table_k, dim3((Ll * 64) / 256), dim3(256), 0, stream, table);
  hipLaunchKernelGGL(rope_apply_k, dim3((Bb * Ll * Hh * 64) / 256), dim3(256), 0, stream,
                     q, k, table, qrw, krw);
  hipLaunchKernelGGL(vtrans_k, dim3(Bb * NCc * Hh * 16), dim3(256), 0, stream, v, vtw);
  hipLaunchKernelGGL(attn_k, dim3(Bb * NCc * Hh * 16), dim3(256), 0, stream,
                     qrw, krw, vtw, out);
}

// Round 2
// 733.352 us; speedup vs baseline: 1.8427x; 1.8427x over previous
//
#include <hip/hip_runtime.h>
#include <math.h>

// Problem constants (B, L, H, DH, DV) = (4, 4096, 16, 128, 128), CHUNK=1024
#define Bb   4
#define Ll   4096
#define Hh   16
#define DHd  128
#define DVd  128
#define CHk  1024
#define NCc  4

typedef __bf16 bf16x8 __attribute__((ext_vector_type(8)));
typedef float  f32x4  __attribute__((ext_vector_type(4)));

static __device__ __forceinline__ unsigned short f32_to_bf16(float f) {
  unsigned int u = __float_as_uint(f);
  u += 0x7FFFu + ((u >> 16) & 1u);   // round-to-nearest-even
  return (unsigned short)(u >> 16);
}

// async global->LDS, 16B per lane; LDS dest = wave-uniform base + lane*16
#define GLDS16(src, dst) \
  __builtin_amdgcn_global_load_lds((const __attribute__((address_space(1))) void*)(src), \
                                   (__attribute__((address_space(3))) void*)(dst), 16, 0, 0)

// ---------------- kernel 1: RoPE cos/sin table [L][64] ----------------
__global__ void rope_table_k(float2* __restrict__ table) {
  int idx = blockIdx.x * 256 + threadIdx.x;
  if (idx >= Ll * 64) return;
  int l = idx >> 6, j = idx & 63;
  float inv_freq = expf((float)j * (-logf(10000.0f) / 64.0f));
  float ang = (float)l * inv_freq;
  float s, c;
  sincosf(ang, &s, &c);
  table[idx] = make_float2(c, s);
}

// ---------- kernel 2: RoPE + scale + bf16 cast for q and k (vectorized) ----------
__global__ void rope_apply_k(const float4* __restrict__ q4, const float4* __restrict__ k4,
                             const float4* __restrict__ tb4,
                             ushort4* __restrict__ qr4, ushort4* __restrict__ kr4) {
  int idx = blockIdx.x * 256 + threadIdx.x;     // B*L*H*16 threads
  int j4 = idx & 15;                            // group of 4 j-values
  int h  = (idx >> 4) & (Hh - 1);
  int l  = (idx >> 8) & (Ll - 1);
  int b  = idx >> 20;
  long base4 = ((long)((b * Ll + l) * Hh + h)) * 32;   // float4 units per row = 32
  float4 cs0 = tb4[l * 32 + j4 * 2];      // c0 s0 c1 s1
  float4 cs1 = tb4[l * 32 + j4 * 2 + 1];  // c2 s2 c3 s3
  float4 a1 = q4[base4 + j4];
  float4 a2 = q4[base4 + 16 + j4];
  float4 b1 = k4[base4 + j4];
  float4 b2 = k4[base4 + 16 + j4];
  const float sc = 0.08838834764831845f;  // 1/sqrt(128), folded into q
  ushort4 o;
  o.x = f32_to_bf16((a1.x * cs0.x - a2.x * cs0.y) * sc);
  o.y = f32_to_bf16((a1.y * cs0.z - a2.y * cs0.w) * sc);
  o.z = f32_to_bf16((a1.z * cs1.x - a2.z * cs1.y) * sc);
  o.w = f32_to_bf16((a1.w * cs1.z - a2.w * cs1.w) * sc);
  qr4[base4 + j4] = o;
  o.x = f32_to_bf16((a1.x * cs0.y + a2.x * cs0.x) * sc);
  o.y = f32_to_bf16((a1.y * cs0.w + a2.y * cs0.z) * sc);
  o.z = f32_to_bf16((a1.z * cs1.y + a2.z * cs1.x) * sc);
  o.w = f32_to_bf16((a1.w * cs1.w + a2.w * cs1.z) * sc);
  qr4[base4 + 16 + j4] = o;
  o.x = f32_to_bf16(b1.x * cs0.x - b2.x * cs0.y);
  o.y = f32_to_bf16(b1.y * cs0.z - b2.y * cs0.w);
  o.z = f32_to_bf16(b1.z * cs1.x - b2.z * cs1.y);
  o.w = f32_to_bf16(b1.w * cs1.z - b2.w * cs1.w);
  kr4[base4 + j4] = o;
  o.x = f32_to_bf16(b1.x * cs0.y + b2.x * cs0.x);
  o.y = f32_to_bf16(b1.y * cs0.w + b2.y * cs0.z);
  o.z = f32_to_bf16(b1.z * cs1.y + b2.z * cs1.x);
  o.w = f32_to_bf16(b1.w * cs1.w + b2.w * cs1.z);
  kr4[base4 + 16 + j4] = o;
}

// ------- kernel 3: V -> bf16, transposed per (b,n,h): vt[dv][kv] -------
__global__ void vtrans_k(const float4* __restrict__ v4, unsigned short* __restrict__ vt) {
  int bid = blockIdx.x;            // (b,n,h,kb): 4*4*16*16 = 4096 blocks
  int kb = bid & 15;               // 64-row kv block
  int h  = (bid >> 4) & 15;
  int n  = (bid >> 8) & 3;
  int b  = bid >> 10;
  __shared__ __align__(16) unsigned short tile[DVd][68];   // row = 136B (8B aligned)
  int tid = threadIdx.x;
#pragma unroll
  for (int it = 0; it < 8; ++it) {
    int i4 = it * 256 + tid;       // 2048 float4 = 64 kv rows x 32
    int r  = i4 >> 5;              // kv row in block
    int c4 = i4 & 31;              // dv quad
    float4 val = v4[((long)((b * Ll + n * CHk + kb * 64 + r) * Hh + h)) * 32 + c4];
    tile[c4 * 4 + 0][r] = f32_to_bf16(val.x);
    tile[c4 * 4 + 1][r] = f32_to_bf16(val.y);
    tile[c4 * 4 + 2][r] = f32_to_bf16(val.z);
    tile[c4 * 4 + 3][r] = f32_to_bf16(val.w);
  }
  __syncthreads();
  long ob = ((long)((b * NCc + n) * Hh + h)) * (DVd * CHk) + kb * 64;
#pragma unroll
  for (int it = 0; it < 8; ++it) {
    int i4 = it * 256 + tid;       // 2048 ushort4 = 128 dv x 16
    int dv  = i4 >> 4;
    int k4i = i4 & 15;
    ushort4 o = *(const ushort4*)&tile[dv][k4i * 4];
    *(ushort4*)&vt[ob + (long)dv * CHk + k4i * 4] = o;
  }
}

// ---- staging: K tile [64][128] + Vt tile [128][64], XOR-swizzled via source ----
__device__ __forceinline__ void stage_kv(const unsigned short* krb, const unsigned short* vtb,
                                         unsigned short* Kb, unsigned short* Vb,
                                         int kvb, int tid) {
  int wbase = tid & 192;           // wid*64 (wave-uniform)
#pragma unroll
  for (int i = 0; i < 4; ++i) {
    int t = i * 256 + tid;
    int row = t >> 4;                        // kv 0..63
    int c16 = (t & 15) ^ ((t >> 4) & 7);     // inverse swizzle on source
    const char* src = (const char*)(krb + (long)(kvb + row) * (Hh * DHd)) + c16 * 16;
    char* dst = (char*)Kb + (i * 256 + wbase) * 16;
    GLDS16(src, dst);
  }
#pragma unroll
  for (int i = 0; i < 4; ++i) {
    int t = i * 256 + tid;
    int row = t >> 3;                        // dv 0..127
    int c16 = (t & 7) ^ ((t >> 3) & 7);
    const char* src = (const char*)(vtb + (long)row * CHk + kvb) + c16 * 16;
    char* dst = (char*)Vb + (i * 256 + wbase) * 16;
    GLDS16(src, dst);
  }
}

// ---------------- kernel 4: chunk-causal flash attention ----------------
// 4 waves, 64 q-rows/block (16/wave), KV tiles of 64, LDS-staged + dbuf.
__global__ __launch_bounds__(256, 2)
void attn_k(const unsigned short* __restrict__ qr,
            const unsigned short* __restrict__ kr,
            const unsigned short* __restrict__ vt,
            float* __restrict__ out) {
  __shared__ __align__(16) unsigned short Klds[2][64 * 128];   // swizzled
  __shared__ __align__(16) unsigned short Vlds[2][128 * 64];   // swizzled
  __shared__ __align__(16) unsigned short plds[4][16][72];     // per-wave P, padded

  int bid = blockIdx.x;
  int qt = 15 - (bid & 15);        // reversed: heavy blocks first
  int h  = (bid >> 4) & 15;
  int n  = (bid >> 8) & 3;
  int b  = bid >> 10;
  int tid  = threadIdx.x;
  int wid  = tid >> 6;
  int lane = tid & 63;
  int lg = lane >> 4;
  int lc = lane & 15;

  const unsigned short* krb = kr + ((long)((b * Ll + n * CHk) * Hh + h)) * DHd;
  const unsigned short* vtb = vt + ((long)((b * NCc + n) * Hh + h)) * (DVd * CHk);

  int qrow0 = qt * 64 + wid * 16;
  const unsigned short* qrow =
      qr + ((long)((b * Ll + n * CHk + qrow0 + lc) * Hh + h)) * DHd;
  bf16x8 qf[4];
#pragma unroll
  for (int ks = 0; ks < 4; ++ks)
    qf[ks] = *reinterpret_cast<const bf16x8*>(qrow + ks * 32 + lg * 8);

  f32x4 oacc[8];
#pragma unroll
  for (int i = 0; i < 8; ++i) oacc[i] = (f32x4){0.f, 0.f, 0.f, 0.f};
  float mrow[4], lrow[4];
#pragma unroll
  for (int r = 0; r < 4; ++r) { mrow[r] = -3.0e38f; lrow[r] = 0.f; }

  // prologue: stage tile 0 into buf 0
  stage_kv(krb, vtb, &Klds[0][0], &Vlds[0][0], 0, tid);
  __syncthreads();

  int cur = 0;
  int swz = (lc & 7) << 4;         // read-side XOR swizzle (row low bits = lc low bits)
  for (int kvt = 0; kvt <= qt; ++kvt) {
    int kvb = kvt * 64;
    if (kvt < qt)
      stage_kv(krb, vtb, &Klds[cur ^ 1][0], &Vlds[cur ^ 1][0], kvb + 64, tid);

    // ---- S = Q K^T over 64 kv cols (4 D-tiles of 16) ----
    const char* Kb = (const char*)&Klds[cur][0];
    f32x4 sacc[4];
#pragma unroll
    for (int ct = 0; ct < 4; ++ct) sacc[ct] = (f32x4){0.f, 0.f, 0.f, 0.f};
#pragma unroll
    for (int ct = 0; ct < 4; ++ct) {
      int rowb = (ct * 16 + lc) * 256;
#pragma unroll
      for (int ks = 0; ks < 4; ++ks) {
        bf16x8 kf = *(const bf16x8*)(Kb + rowb + ((ks * 64 + lg * 16) ^ swz));
        sacc[ct] = __builtin_amdgcn_mfma_f32_16x16x32_bf16(qf[ks], kf, sacc[ct], 0, 0, 0);
      }
    }

    // ---- causal mask (diagonal tile only) + online softmax ----
    float p[4][4];
#pragma unroll
    for (int ct = 0; ct < 4; ++ct)
#pragma unroll
      for (int r = 0; r < 4; ++r) p[ct][r] = sacc[ct][r];
    if (kvt == qt) {
#pragma unroll
      for (int ct = 0; ct < 4; ++ct) {
        int col = kvb + ct * 16 + lc;
#pragma unroll
        for (int r = 0; r < 4; ++r)
          if (col > qrow0 + lg * 4 + r) p[ct][r] = -3.0e38f;
      }
    }
#pragma unroll
    for (int r = 0; r < 4; ++r) {
      float tmax = fmaxf(fmaxf(p[0][r], p[1][r]), fmaxf(p[2][r], p[3][r]));
      tmax = fmaxf(tmax, __shfl_xor(tmax, 1));
      tmax = fmaxf(tmax, __shfl_xor(tmax, 2));
      tmax = fmaxf(tmax, __shfl_xor(tmax, 4));
      tmax = fmaxf(tmax, __shfl_xor(tmax, 8));
      float mnew = fmaxf(mrow[r], tmax);
      float corr = __expf(mrow[r] - mnew);
      mrow[r] = mnew;
      float ps = 0.f;
#pragma unroll
      for (int ct = 0; ct < 4; ++ct) {
        p[ct][r] = __expf(p[ct][r] - mnew);
        ps += p[ct][r];
      }
      ps += __shfl_xor(ps, 1);
      ps += __shfl_xor(ps, 2);
      ps += __shfl_xor(ps, 4);
      ps += __shfl_xor(ps, 8);
      lrow[r] = lrow[r] * corr + ps;
#pragma unroll
      for (int dt = 0; dt < 8; ++dt) oacc[dt][r] *= corr;
    }

    // ---- P (D-layout) -> per-wave LDS -> A-fragment layout ----
#pragma unroll
    for (int ct = 0; ct < 4; ++ct)
#pragma unroll
      for (int r = 0; r < 4; ++r)
        plds[wid][lg * 4 + r][ct * 16 + lc] = f32_to_bf16(p[ct][r]);
    // same-wave DS ops are in-order; aliasing orders write->read
    const char* Pb = (const char*)&plds[wid][0][0];
    bf16x8 pf0 = *(const bf16x8*)(Pb + lc * 144 + lg * 16);
    bf16x8 pf1 = *(const bf16x8*)(Pb + lc * 144 + 64 + lg * 16);

    // ---- O += P V (8 dv-tiles of 16, two k-halves) ----
    const char* Vb = (const char*)&Vlds[cur][0];
#pragma unroll
    for (int dt = 0; dt < 8; ++dt) {
      int rowb = (dt * 16 + lc) * 128;
      bf16x8 vf0 = *(const bf16x8*)(Vb + rowb + ((lg * 16) ^ swz));
      bf16x8 vf1 = *(const bf16x8*)(Vb + rowb + ((64 + lg * 16) ^ swz));
      oacc[dt] = __builtin_amdgcn_mfma_f32_16x16x32_bf16(pf0, vf0, oacc[dt], 0, 0, 0);
      oacc[dt] = __builtin_amdgcn_mfma_f32_16x16x32_bf16(pf1, vf1, oacc[dt], 0, 0, 0);
    }

    __syncthreads();               // drains vmcnt (stage) + lgkmcnt; swap buffers
    cur ^= 1;
  }

  // ---- epilogue: normalize and store f32 ----
  long ob = (long)(b * Ll + n * CHk + qrow0 + lg * 4) * (Hh * DVd) + h * DVd + lc;
#pragma unroll
  for (int r = 0; r < 4; ++r) {
    float invl = 1.0f / lrow[r];
#pragma unroll
    for (int dt = 0; dt < 8; ++dt)
      out[ob + (long)r * (Hh * DVd) + dt * 16] = oacc[dt][r] * invl;
  }
}

extern "C" void kernel_launch(void* const* d_in, const int* in_sizes, int n_in,
                              void* d_out, int out_size, void* d_ws, size_t ws_size,
                              hipStream_t stream) {
  const float* q = (const float*)d_in[0];
  const float* k = (const float*)d_in[1];
  const float* v = (const float*)d_in[2];
  float* out = (float*)d_out;

  // workspace layout: table(2MB) | qr(67MB) | kr(67MB) | vt(67MB)
  char* ws = (char*)d_ws;
  float2* table = (float2*)ws;
  unsigned short* qrw = (unsigned short*)(ws + (2l << 20));
  unsigned short* krw = qrw + (long)Bb * Ll * Hh * DHd;
  unsigned short* vtw = krw + (long)Bb * Ll * Hh * DHd;

  hipLaunchKernelGGL(rope_table_k, dim3((Ll * 64) / 256), dim3(256), 0, stream, table);
  hipLaunchKernelGGL(rope_apply_k, dim3((Bb * Ll * Hh * 16) / 256), dim3(256), 0, stream,
                     (const float4*)q, (const float4*)k, (const float4*)table,
                     (ushort4*)qrw, (ushort4*)krw);
  hipLaunchKernelGGL(vtrans_k, dim3(Bb * NCc * Hh * 16), dim3(256), 0, stream,
                     (const float4*)v, vtw);
  hipLaunchKernelGGL(attn_k, dim3(Bb * NCc * Hh * 16), dim3(256), 0, stream,
                     qrw, krw, vtw, out);
}